// Round 1
// baseline (729.792 us; speedup 1.0000x reference)
//
#include <hip/hip_runtime.h>
#include <math.h>

#define B_ 16
#define C_ 256
#define H_ 128
#define W_ 128
#define HW_ (H_*W_)
#define PO 20
#define NPOOL (PO*PO)
#define MID_ 16
#define OC_ 32
#define OH_ 64
#define OW_ 64
#define BN_EPS 1e-3f

// workspace offsets in floats (total ~10.82M floats = 43.3 MB)
#define OFF_XP     0
#define OFF_FEAT   1638400
#define OFF_SCORE  1642496
#define OFF_MAXID  1642752
#define OFF_SCALE  1642768
#define OFF_BNSUM  1642784
#define OFF_BNSQ   1642816
#define OFF_BNSC   1642848
#define OFF_BNSH   1642880
#define OFF_SMEAN  1642912
#define OFF_SMAX   1905056
#define OFF_SIGA   2167200
#define OFF_XC     2429344

// ---------------- 1. adaptive avg pool 128x128 -> 20x20 per (b,c) plane ----
// Row bins split exactly at h=64 (bin9 ends at ceil(10*6.4)=64, bin10 starts
// at floor(10*6.4)=64), so we can stage half planes (32KB LDS) at a time.
__global__ __launch_bounds__(256) void k_pool(const float* __restrict__ x,
                                              float* __restrict__ xp) {
  __shared__ __attribute__((aligned(16))) float plane[64 * W_]; // 32 KB
  __shared__ float tmp[64 * PO];                                // 5 KB
  const int pid = blockIdx.x; // b*C + c
  const float* src = x + (size_t)pid * HW_;
  float* outp = xp + (size_t)pid * NPOOL;
  for (int half = 0; half < 2; ++half) {
    const float4* s4 = (const float4*)(src + half * 64 * W_);
    for (int i = threadIdx.x; i < 64 * W_ / 4; i += 256)
      ((float4*)plane)[i] = s4[i];
    __syncthreads();
    for (int i = threadIdx.x; i < 64 * PO; i += 256) {
      int h = i / PO, p = i % PO;
      int cs = (p * W_) / PO, ce = ((p + 1) * W_ + PO - 1) / PO;
      float s = 0.f;
      for (int c = cs; c < ce; ++c) s += plane[h * W_ + c];
      tmp[i] = s / (float)(ce - cs);
    }
    __syncthreads();
    for (int i = threadIdx.x; i < NPOOL / 2; i += 256) {
      int o = half * 10 + i / PO, p = i % PO;
      int rs = (o * H_) / PO, re = ((o + 1) * H_ + PO - 1) / PO;
      float s = 0.f;
      for (int r = rs; r < re; ++r) s += tmp[(r - half * 64) * PO + p];
      outp[o * PO + p] = s / (float)(re - rs);
    }
    __syncthreads();
  }
}

// ---------------- 2. feat[b,i] = (1/(399*256)) * (sum_n xp[i,n]*s[n] - m_i*S)
__global__ __launch_bounds__(256) void k_feat(const float* __restrict__ xp,
                                              float* __restrict__ feat) {
  const int b = blockIdx.x;
  const float* base = xp + (size_t)b * C_ * NPOOL;
  const int tid = threadIdx.x;
  __shared__ float sn[NPOOL];
  __shared__ float red[256];
  const float* row = base + tid * NPOOL;
  float rs = 0.f;
  for (int n = 0; n < NPOOL; ++n) rs += row[n];
  float m = rs / (float)NPOOL;
  red[tid] = m;
  __syncthreads();
  for (int s = 128; s > 0; s >>= 1) {
    if (tid < s) red[tid] += red[tid + s];
    __syncthreads();
  }
  float totm = red[0];  // sum over channels of per-channel mean
  // column sums -> s[n]
  for (int n = tid; n < NPOOL; n += 256) {
    float cs = 0.f;
    for (int c = 0; c < C_; ++c) cs += base[c * NPOOL + n];
    sn[n] = cs - totm;
  }
  __syncthreads();
  float Sl = 0.f;
  for (int n = tid; n < NPOOL; n += 256) Sl += sn[n];
  red[tid] = Sl;
  __syncthreads();
  for (int s = 128; s > 0; s >>= 1) {
    if (tid < s) red[tid] += red[tid + s];
    __syncthreads();
  }
  float S = red[0]; // ~0 analytically; kept for fp fidelity
  float acc = 0.f;
  for (int n = 0; n < NPOOL; ++n) acc += row[n] * sn[n];
  feat[b * C_ + tid] = (acc - m * S) / ((float)(NPOOL - 1) * (float)C_);
}

// ---------------- 3. score[j] = mean_b sigmoid(feat[b,:] . W[j,:] + bias[j])
__global__ __launch_bounds__(256) void k_score(const float* __restrict__ feat,
                                               const float* __restrict__ lw,
                                               const float* __restrict__ lb,
                                               float* __restrict__ score) {
  __shared__ float sf[B_ * C_]; // 16 KB
  const int tid = threadIdx.x;
  for (int i = tid; i < B_ * C_; i += 256) sf[i] = feat[i];
  __syncthreads();
  const float* wrow = lw + (size_t)tid * C_;
  float bias = lb[tid];
  float ssum = 0.f;
  for (int b = 0; b < B_; ++b) {
    float z = 0.f;
    for (int i = 0; i < C_; ++i) z += sf[b * C_ + i] * wrow[i];
    z += bias;
    ssum += 1.0f / (1.0f + expf(-z)); // accurate expf: score gaps ~1e-6
  }
  score[tid] = ssum / (float)B_;
}

// ---------------- 4. stable top-16 (descending, ties by index), sorted asc
__global__ __launch_bounds__(256) void k_select(const float* __restrict__ score,
                                                int* __restrict__ max_id,
                                                float* __restrict__ scale) {
  __shared__ float ss[C_];
  __shared__ int flag[C_];
  const int tid = threadIdx.x;
  ss[tid] = score[tid];
  __syncthreads();
  float my = ss[tid];
  int rank = 0;
  for (int k = 0; k < C_; ++k) {
    float v = ss[k];
    rank += (v > my || (v == my && k < tid)) ? 1 : 0;
  }
  flag[tid] = (rank < MID_) ? 1 : 0;
  __syncthreads();
  if (rank < MID_) {
    int pos = 0;
    for (int k = 0; k < tid; ++k) pos += flag[k];
    max_id[pos] = tid;
    scale[pos] = 1.0f + my;
  }
}

// ---------------- 5. build xc = [gathered*scale ; group means], + mean/max --
__global__ __launch_bounds__(256) void k_build(const float* __restrict__ x,
                                               const int* __restrict__ max_id,
                                               const float* __restrict__ scale,
                                               float* __restrict__ xc,
                                               float* __restrict__ smean,
                                               float* __restrict__ smax) {
  __shared__ int mid_s[MID_];
  __shared__ float sc_s[MID_];
  if (threadIdx.x < MID_) {
    mid_s[threadIdx.x] = max_id[threadIdx.x];
    sc_s[threadIdx.x] = scale[threadIdx.x];
  }
  __syncthreads();
  int idx4 = blockIdx.x * 256 + threadIdx.x; // over B*HW/4 = 65536
  int b = idx4 >> 12;
  int pix4 = idx4 & 4095;
  const float4* xb = (const float4*)x + (size_t)b * C_ * (HW_ / 4) + pix4;
  float4* xco = (float4*)xc + (size_t)b * OC_ * (HW_ / 4) + pix4;
  float4 msum = make_float4(0.f, 0.f, 0.f, 0.f);
  float4 mx = make_float4(-INFINITY, -INFINITY, -INFINITY, -INFINITY);
#pragma unroll
  for (int m = 0; m < MID_; ++m) {
    float4 t = xb[(size_t)mid_s[m] * (HW_ / 4)];
    float s = sc_s[m];
    t.x *= s; t.y *= s; t.z *= s; t.w *= s;
    xco[(size_t)m * (HW_ / 4)] = t;
    msum.x += t.x; msum.y += t.y; msum.z += t.z; msum.w += t.w;
    mx.x = fmaxf(mx.x, t.x); mx.y = fmaxf(mx.y, t.y);
    mx.z = fmaxf(mx.z, t.z); mx.w = fmaxf(mx.w, t.w);
  }
#pragma unroll
  for (int g = 0; g < MID_; ++g) {
    float4 a = make_float4(0.f, 0.f, 0.f, 0.f);
#pragma unroll
    for (int i = 0; i < 16; ++i) {
      float4 t = xb[(size_t)(g * 16 + i) * (HW_ / 4)];
      a.x += t.x; a.y += t.y; a.z += t.z; a.w += t.w;
    }
    a.x *= 0.0625f; a.y *= 0.0625f; a.z *= 0.0625f; a.w *= 0.0625f;
    xco[(size_t)(MID_ + g) * (HW_ / 4)] = a;
    msum.x += a.x; msum.y += a.y; msum.z += a.z; msum.w += a.w;
    mx.x = fmaxf(mx.x, a.x); mx.y = fmaxf(mx.y, a.y);
    mx.z = fmaxf(mx.z, a.z); mx.w = fmaxf(mx.w, a.w);
  }
  float4 sm = make_float4(msum.x * (1.f / 32.f), msum.y * (1.f / 32.f),
                          msum.z * (1.f / 32.f), msum.w * (1.f / 32.f));
  ((float4*)smean)[idx4] = sm;
  ((float4*)smax)[idx4] = mx;
}

// ---------------- 6. LSA 7x7 conv (2->1) pad 3 + sigmoid ------------------
__global__ __launch_bounds__(256) void k_lsa(const float* __restrict__ smean,
                                             const float* __restrict__ smax,
                                             const float* __restrict__ lsa_w,
                                             float* __restrict__ siga) {
  __shared__ float w0[49], w1[49];
  if (threadIdx.x < 49) {
    w0[threadIdx.x] = lsa_w[threadIdx.x];
    w1[threadIdx.x] = lsa_w[49 + threadIdx.x];
  }
  __syncthreads();
  int idx = blockIdx.x * 256 + threadIdx.x; // over B*HW
  int b = idx >> 14;
  int pix = idx & (HW_ - 1);
  int h = pix >> 7, w = pix & 127;
  const float* pm = smean + (size_t)b * HW_;
  const float* px = smax + (size_t)b * HW_;
  float acc = 0.f;
  for (int kh = 0; kh < 7; ++kh) {
    int ih = h + kh - 3;
    if (ih < 0 || ih >= H_) continue;
    for (int kw = 0; kw < 7; ++kw) {
      int iw = w + kw - 3;
      if (iw < 0 || iw >= W_) continue;
      int p = ih * W_ + iw;
      acc += pm[p] * w0[kh * 7 + kw] + px[p] * w1[kh * 7 + kw];
    }
  }
  siga[idx] = 1.0f / (1.0f + __expf(-acc));
}

// ---------------- 7. conv 3x3 stride2 pad1 (32->32) + bias + BN partials ---
// block = (b, 4 output rows). threads: oc = tid&31, ow-octet g = tid>>5.
// weights in LDS transposed [ic*9+k][oc] (lane-consecutive -> conflict-free);
// input rows register-cached (5x float4), LDS reads broadcast across oc lanes.
__global__ __launch_bounds__(256) void k_conv(const float* __restrict__ xc,
                                              const float* __restrict__ siga,
                                              const float* __restrict__ conv_w,
                                              const float* __restrict__ conv_b,
                                              float* __restrict__ out,
                                              float* __restrict__ bnsum,
                                              float* __restrict__ bnsq) {
  __shared__ __attribute__((aligned(16))) float in_lds[4 * 9 * 132]; // 19 KB
  __shared__ float w_lds[288 * 32];                                  // 36 KB
  const int tid = threadIdx.x;
  const int oc = tid & 31;
  const int g = tid >> 5;
  const int b = blockIdx.x >> 4;
  const int oh0 = (blockIdx.x & 15) * 4;
  const int ih0 = 2 * oh0 - 1;

  for (int i = tid; i < 288 * 32; i += 256) {
    int oc_ = i / 288, rem = i % 288;
    w_lds[rem * 32 + oc_] = conv_w[i];
  }

  float acc[4][8];
#pragma unroll
  for (int a = 0; a < 4; ++a)
#pragma unroll
    for (int o = 0; o < 8; ++o) acc[a][o] = 0.f;

  const float* sgb = siga + (size_t)b * HW_;

  for (int chunk = 0; chunk < 8; ++chunk) {
    __syncthreads();
    for (int i = tid; i < 4 * 9 * 132; i += 256) {
      int icl = i / (9 * 132);
      int rem = i % (9 * 132);
      int r = rem / 132, col = rem % 132;
      int ih = ih0 + r, iw = col - 1;
      float v = 0.f;
      if (ih >= 0 && ih < H_ && iw >= 0 && iw < W_) {
        int p = ih * W_ + iw;
        v = xc[((size_t)b * OC_ + (chunk * 4 + icl)) * HW_ + p] * sgb[p];
      }
      in_lds[i] = v;
    }
    __syncthreads();
#pragma unroll
    for (int icl = 0; icl < 4; ++icl) {
      const int wb = (chunk * 4 + icl) * 9 * 32 + oc;
#pragma unroll
      for (int r = 0; r < 9; ++r) {
        float f[20] __attribute__((aligned(16)));
        const float4* s4 = (const float4*)&in_lds[(icl * 9 + r) * 132 + 16 * g];
#pragma unroll
        for (int j = 0; j < 5; ++j) ((float4*)f)[j] = s4[j];
#pragma unroll
        for (int ohl = 0; ohl < 4; ++ohl) {
          const int kh = r - 2 * ohl;
          if (kh < 0 || kh > 2) continue; // compile-time after unroll
          float w0 = w_lds[wb + (kh * 3 + 0) * 32];
          float w1 = w_lds[wb + (kh * 3 + 1) * 32];
          float w2 = w_lds[wb + (kh * 3 + 2) * 32];
#pragma unroll
          for (int o = 0; o < 8; ++o)
            acc[ohl][o] += f[2 * o] * w0 + f[2 * o + 1] * w1 + f[2 * o + 2] * w2;
        }
      }
    }
  }

  float bias = conv_b[oc];
  float lsum = 0.f, lsq = 0.f;
  float* outp = out + ((size_t)b * OC_ + oc) * (OH_ * OW_) + (size_t)oh0 * OW_ + g * 8;
#pragma unroll
  for (int ohl = 0; ohl < 4; ++ohl) {
    float vout[8] __attribute__((aligned(16)));
#pragma unroll
    for (int o = 0; o < 8; ++o) {
      float v = acc[ohl][o] + bias;
      vout[o] = v;
      lsum += v;
      lsq += v * v;
    }
    *((float4*)(outp + ohl * OW_)) = *(float4*)&vout[0];
    *((float4*)(outp + ohl * OW_ + 4)) = *(float4*)&vout[4];
  }
  __syncthreads(); // everyone done reading in_lds; reuse for reduction
  in_lds[tid] = lsum;
  in_lds[256 + tid] = lsq;
  __syncthreads();
  if (tid < 32) {
    float t = 0.f, tq = 0.f;
#pragma unroll
    for (int gg = 0; gg < 8; ++gg) {
      t += in_lds[gg * 32 + tid];
      tq += in_lds[256 + gg * 32 + tid];
    }
    atomicAdd(&bnsum[tid], t);
    atomicAdd(&bnsq[tid], tq);
  }
}

// ---------------- 8. finalize BN scale/shift -------------------------------
__global__ void k_bnfin(const float* __restrict__ sum, const float* __restrict__ sq,
                        const float* __restrict__ gamma, const float* __restrict__ beta,
                        float* __restrict__ bnsc, float* __restrict__ bnsh) {
  int i = threadIdx.x;
  if (i < OC_) {
    const float N = (float)(B_ * OH_ * OW_);
    float mu = sum[i] / N;
    float var = sq[i] / N - mu * mu; // population var (ddof=0)
    float sc = gamma[i] / sqrtf(var + BN_EPS);
    bnsc[i] = sc;
    bnsh[i] = beta[i] - mu * sc;
  }
}

// ---------------- 9. apply BN + SiLU in place ------------------------------
__global__ __launch_bounds__(256) void k_apply(float* __restrict__ out,
                                               const float* __restrict__ bnsc,
                                               const float* __restrict__ bnsh) {
  int idx4 = blockIdx.x * 256 + threadIdx.x; // over out_size/4 = 524288
  int oc = (idx4 >> 10) & 31;                // 1024 float4 per (b,oc) plane
  float sc = bnsc[oc], sh = bnsh[oc];
  float4 v = ((float4*)out)[idx4];
  float t;
  t = v.x * sc + sh; v.x = t / (1.0f + __expf(-t));
  t = v.y * sc + sh; v.y = t / (1.0f + __expf(-t));
  t = v.z * sc + sh; v.z = t / (1.0f + __expf(-t));
  t = v.w * sc + sh; v.w = t / (1.0f + __expf(-t));
  ((float4*)out)[idx4] = v;
}

extern "C" void kernel_launch(void* const* d_in, const int* in_sizes, int n_in,
                              void* d_out, int out_size, void* d_ws, size_t ws_size,
                              hipStream_t stream) {
  const float* x      = (const float*)d_in[0];
  const float* lw     = (const float*)d_in[1];
  const float* lb     = (const float*)d_in[2];
  const float* lsa_w  = (const float*)d_in[3];
  const float* conv_w = (const float*)d_in[4];
  const float* conv_b = (const float*)d_in[5];
  const float* gamma  = (const float*)d_in[6];
  const float* beta   = (const float*)d_in[7];
  float* out = (float*)d_out;
  float* ws = (float*)d_ws;

  hipMemsetAsync(ws + OFF_BNSUM, 0, 64 * sizeof(float), stream); // sums+sumsq

  k_pool<<<B_ * C_, 256, 0, stream>>>(x, ws + OFF_XP);
  k_feat<<<B_, 256, 0, stream>>>(ws + OFF_XP, ws + OFF_FEAT);
  k_score<<<1, 256, 0, stream>>>(ws + OFF_FEAT, lw, lb, ws + OFF_SCORE);
  k_select<<<1, 256, 0, stream>>>(ws + OFF_SCORE, (int*)(ws + OFF_MAXID), ws + OFF_SCALE);
  k_build<<<256, 256, 0, stream>>>(x, (const int*)(ws + OFF_MAXID), ws + OFF_SCALE,
                                   ws + OFF_XC, ws + OFF_SMEAN, ws + OFF_SMAX);
  k_lsa<<<1024, 256, 0, stream>>>(ws + OFF_SMEAN, ws + OFF_SMAX, lsa_w, ws + OFF_SIGA);
  k_conv<<<B_ * 16, 256, 0, stream>>>(ws + OFF_XC, ws + OFF_SIGA, conv_w, conv_b, out,
                                      ws + OFF_BNSUM, ws + OFF_BNSQ);
  k_bnfin<<<1, 64, 0, stream>>>(ws + OFF_BNSUM, ws + OFF_BNSQ, gamma, beta,
                                ws + OFF_BNSC, ws + OFF_BNSH);
  k_apply<<<2048, 256, 0, stream>>>(out, ws + OFF_BNSC, ws + OFF_BNSH);
}

// Round 2
// 677.376 us; speedup vs baseline: 1.0774x; 1.0774x over previous
//
#include <hip/hip_runtime.h>
#include <math.h>

#define B_ 16
#define C_ 256
#define H_ 128
#define W_ 128
#define HW_ (H_*W_)
#define PO 20
#define NPOOL (PO*PO)
#define MID_ 16
#define OC_ 32
#define OH_ 64
#define OW_ 64
#define BN_EPS 1e-3f

// workspace offsets in floats (total ~10.82M floats = 43.3 MB)
#define OFF_XP     0
#define OFF_FEAT   1638400
#define OFF_MAXID  1642496
#define OFF_SCALE  1642512
#define OFF_BNSUM  1642528
#define OFF_BNSQ   1642560
#define OFF_SMEAN  1642592
#define OFF_SMAX   1904736
#define OFF_SIGA   2166880
#define OFF_XC     2429024

// adaptive-pool bin start/end for n=128 -> 20 (same for H and W):
// s(p) = floor(p*128/20), e(p) = ceil((p+1)*128/20)
__device__ __forceinline__ int bin_s(int p) { return (p * 128) / 20; }
__device__ __forceinline__ int bin_e(int p) { return ((p + 1) * 128 + 19) / 20; }

// ---------------- 1. adaptive avg pool 128x128 -> 20x20 per (b,c) plane ----
// No full-plane staging: each thread col-pools half a row (64 cols) straight
// from global into 10 register bins (membership folded at compile time),
// writes tmp[128][20] in LDS (10 KB), then row-pools. One barrier total.
__global__ __launch_bounds__(256) void k_pool(const float* __restrict__ x,
                                              float* __restrict__ xp) {
  __shared__ float tmp[128 * PO]; // 10 KB
  const int pid = blockIdx.x;     // b*C + c
  const int t = threadIdx.x;
  const int h = t >> 1, side = t & 1;
  const float4* src4 = (const float4*)(x + (size_t)pid * HW_) + h * 32 + side * 16;

  float bin[10];
#pragma unroll
  for (int p = 0; p < 10; ++p) bin[p] = 0.f;
#pragma unroll
  for (int j = 0; j < 16; ++j) {
    float4 v = src4[j];
    float c4[4] = {v.x, v.y, v.z, v.w};
#pragma unroll
    for (int k = 0; k < 4; ++k) {
      int c = 4 * j + k; // col relative to side*64; bins are half-local
#pragma unroll
      for (int p = 0; p < 10; ++p) {
        // global bin pg = side*10+p covers [bin_s(pg)-64*side, bin_e(pg)-64*side)
        // both halves share the same relative boundaries (boundary at 64 exact)
        int cs = bin_s(p + 10) - 64; // == bin_s(p) for p<10 via symmetry? no:
        (void)cs;
      }
      // resolved below with explicit per-half constants
#pragma unroll
      for (int p = 0; p < 10; ++p) {
        int pg = p; // relative boundaries for side 0
        int s0 = bin_s(pg), e0 = bin_e(pg);
        int s1 = bin_s(pg + 10) - 64, e1 = bin_e(pg + 10) - 64;
        int s = side ? s1 : s0, e = side ? e1 : e0;
        if (c >= s && c < e) bin[p] += c4[k];
      }
    }
  }
#pragma unroll
  for (int p = 0; p < 10; ++p) {
    int pg = side * 10 + p;
    float w = (float)(bin_e(pg) - bin_s(pg));
    tmp[h * PO + pg] = bin[p] / w;
  }
  __syncthreads();
  float* outp = xp + (size_t)pid * NPOOL;
  for (int i = t; i < NPOOL; i += 256) {
    int o = i / PO, p = i % PO;
    int rs = bin_s(o), re = bin_e(o);
    float s = 0.f;
    for (int r = rs; r < re; ++r) s += tmp[r * PO + p];
    outp[i] = s / (float)(re - rs);
  }
}

// ---------------- 2. feat[b,i] = (1/(399*256)) * (sum_n xp[i,n]*s[n] - m_i*S)
__global__ __launch_bounds__(256) void k_feat(const float* __restrict__ xp,
                                              float* __restrict__ feat) {
  const int b = blockIdx.x;
  const float* base = xp + (size_t)b * C_ * NPOOL;
  const int tid = threadIdx.x;
  __shared__ float sn[NPOOL];
  __shared__ float red[256];
  const float* row = base + tid * NPOOL;
  float rs = 0.f;
  for (int n = 0; n < NPOOL; ++n) rs += row[n];
  float m = rs / (float)NPOOL;
  red[tid] = m;
  __syncthreads();
  for (int s = 128; s > 0; s >>= 1) {
    if (tid < s) red[tid] += red[tid + s];
    __syncthreads();
  }
  float totm = red[0];
  for (int n = tid; n < NPOOL; n += 256) {
    float cs = 0.f;
    for (int c = 0; c < C_; ++c) cs += base[c * NPOOL + n];
    sn[n] = cs - totm;
  }
  __syncthreads();
  float Sl = 0.f;
  for (int n = tid; n < NPOOL; n += 256) Sl += sn[n];
  red[tid] = Sl;
  __syncthreads();
  for (int s = 128; s > 0; s >>= 1) {
    if (tid < s) red[tid] += red[tid + s];
    __syncthreads();
  }
  float S = red[0];
  float acc = 0.f;
  for (int n = 0; n < NPOOL; ++n) acc += row[n] * sn[n];
  feat[b * C_ + tid] = (acc - m * S) / ((float)(NPOOL - 1) * (float)C_);
}

// ---------------- 3+4. score = mean_b sigmoid(feat@W^T+b); stable top-16 ---
__global__ __launch_bounds__(256) void k_attn(const float* __restrict__ feat,
                                              const float* __restrict__ lw,
                                              const float* __restrict__ lb,
                                              int* __restrict__ max_id,
                                              float* __restrict__ scale) {
  __shared__ float sf[B_ * C_]; // 16 KB
  __shared__ float ss[C_];
  __shared__ int flag[C_];
  const int tid = threadIdx.x;
  for (int i = tid; i < B_ * C_; i += 256) sf[i] = feat[i];
  __syncthreads();
  const float* wrow = lw + (size_t)tid * C_;
  float bias = lb[tid];
  float ssum = 0.f;
  for (int b = 0; b < B_; ++b) {
    float z = 0.f;
    for (int i = 0; i < C_; ++i) z += sf[b * C_ + i] * wrow[i];
    z += bias;
    ssum += 1.0f / (1.0f + expf(-z)); // accurate expf: score gaps ~1e-6
  }
  float my = ssum / (float)B_;
  ss[tid] = my;
  __syncthreads();
  int rank = 0;
  for (int k = 0; k < C_; ++k) {
    float v = ss[k];
    rank += (v > my || (v == my && k < tid)) ? 1 : 0;
  }
  flag[tid] = (rank < MID_) ? 1 : 0;
  __syncthreads();
  if (rank < MID_) {
    int pos = 0;
    for (int k = 0; k < tid; ++k) pos += flag[k];
    max_id[pos] = tid;
    scale[pos] = 1.0f + my;
  }
}

// ---------------- 5. build xc = [gathered*scale ; group means], + mean/max --
// 4 thread-slices per pix4 (4 gathered + 4 groups each) -> grid 1024 blocks,
// 16 waves/CU. Partials combined in LDS.
__global__ __launch_bounds__(256) void k_build(const float* __restrict__ x,
                                               const int* __restrict__ max_id,
                                               const float* __restrict__ scale,
                                               float* __restrict__ xc,
                                               float* __restrict__ smean,
                                               float* __restrict__ smax) {
  __shared__ int mid_s[MID_];
  __shared__ float sc_s[MID_];
  __shared__ float4 psum[4][64];
  __shared__ float4 pmax[4][64];
  const int tid = threadIdx.x;
  if (tid < MID_) {
    mid_s[tid] = max_id[tid];
    sc_s[tid] = scale[tid];
  }
  __syncthreads();
  const int p = tid & 63, s = tid >> 6;
  const int P = blockIdx.x * 64 + p; // global pix4 in [0, 65536)
  const int b = P >> 12;
  const int pix4 = P & 4095;
  const float4* xb = (const float4*)x + (size_t)b * C_ * (HW_ / 4) + pix4;
  float4* xco = (float4*)xc + (size_t)b * OC_ * (HW_ / 4) + pix4;
  float4 ms = make_float4(0.f, 0.f, 0.f, 0.f);
  float4 mx = make_float4(-INFINITY, -INFINITY, -INFINITY, -INFINITY);
#pragma unroll
  for (int mi = 0; mi < 4; ++mi) {
    int m = 4 * s + mi;
    float4 t = xb[(size_t)mid_s[m] * (HW_ / 4)];
    float sc = sc_s[m];
    t.x *= sc; t.y *= sc; t.z *= sc; t.w *= sc;
    xco[(size_t)m * (HW_ / 4)] = t;
    ms.x += t.x; ms.y += t.y; ms.z += t.z; ms.w += t.w;
    mx.x = fmaxf(mx.x, t.x); mx.y = fmaxf(mx.y, t.y);
    mx.z = fmaxf(mx.z, t.z); mx.w = fmaxf(mx.w, t.w);
  }
#pragma unroll
  for (int gi = 0; gi < 4; ++gi) {
    int g = 4 * s + gi;
    float4 a = make_float4(0.f, 0.f, 0.f, 0.f);
#pragma unroll
    for (int i = 0; i < 16; ++i) {
      float4 t = xb[(size_t)(g * 16 + i) * (HW_ / 4)];
      a.x += t.x; a.y += t.y; a.z += t.z; a.w += t.w;
    }
    a.x *= 0.0625f; a.y *= 0.0625f; a.z *= 0.0625f; a.w *= 0.0625f;
    xco[(size_t)(MID_ + g) * (HW_ / 4)] = a;
    ms.x += a.x; ms.y += a.y; ms.z += a.z; ms.w += a.w;
    mx.x = fmaxf(mx.x, a.x); mx.y = fmaxf(mx.y, a.y);
    mx.z = fmaxf(mx.z, a.z); mx.w = fmaxf(mx.w, a.w);
  }
  psum[s][p] = ms;
  pmax[s][p] = mx;
  __syncthreads();
  if (tid < 64) {
    float4 a0 = psum[0][tid], a1 = psum[1][tid], a2 = psum[2][tid], a3 = psum[3][tid];
    float4 m0 = pmax[0][tid], m1 = pmax[1][tid], m2 = pmax[2][tid], m3 = pmax[3][tid];
    float4 sm, mm;
    sm.x = (a0.x + a1.x + a2.x + a3.x) * (1.f / 32.f);
    sm.y = (a0.y + a1.y + a2.y + a3.y) * (1.f / 32.f);
    sm.z = (a0.z + a1.z + a2.z + a3.z) * (1.f / 32.f);
    sm.w = (a0.w + a1.w + a2.w + a3.w) * (1.f / 32.f);
    mm.x = fmaxf(fmaxf(m0.x, m1.x), fmaxf(m2.x, m3.x));
    mm.y = fmaxf(fmaxf(m0.y, m1.y), fmaxf(m2.y, m3.y));
    mm.z = fmaxf(fmaxf(m0.z, m1.z), fmaxf(m2.z, m3.z));
    mm.w = fmaxf(fmaxf(m0.w, m1.w), fmaxf(m2.w, m3.w));
    int Po = blockIdx.x * 64 + tid;
    ((float4*)smean)[Po] = sm;
    ((float4*)smax)[Po] = mm;
  }
}

// ---------------- 6. LSA 7x7 conv (2->1) pad 3 + sigmoid ------------------
__global__ __launch_bounds__(256) void k_lsa(const float* __restrict__ smean,
                                             const float* __restrict__ smax,
                                             const float* __restrict__ lsa_w,
                                             float* __restrict__ siga) {
  __shared__ float w0[49], w1[49];
  if (threadIdx.x < 49) {
    w0[threadIdx.x] = lsa_w[threadIdx.x];
    w1[threadIdx.x] = lsa_w[49 + threadIdx.x];
  }
  __syncthreads();
  int idx = blockIdx.x * 256 + threadIdx.x; // over B*HW
  int b = idx >> 14;
  int pix = idx & (HW_ - 1);
  int h = pix >> 7, w = pix & 127;
  const float* pm = smean + (size_t)b * HW_;
  const float* px = smax + (size_t)b * HW_;
  float acc = 0.f;
  for (int kh = 0; kh < 7; ++kh) {
    int ih = h + kh - 3;
    if (ih < 0 || ih >= H_) continue;
    for (int kw = 0; kw < 7; ++kw) {
      int iw = w + kw - 3;
      if (iw < 0 || iw >= W_) continue;
      int p = ih * W_ + iw;
      acc += pm[p] * w0[kh * 7 + kw] + px[p] * w1[kh * 7 + kw];
    }
  }
  siga[idx] = 1.0f / (1.0f + __expf(-acc));
}

// ---------------- 7. conv 3x3 stride2 pad1 (32->32) + bias + BN partials ---
// 2-output-row tiles -> grid 512 (2 blocks/CU, 8 waves/CU). Weights staged
// once in LDS transposed [ic*9+k][oc] (broadcast-free reads); input rows
// register-cached from LDS as float4 (broadcast across the 32 oc lanes).
__global__ __launch_bounds__(256) void k_conv(const float* __restrict__ xc,
                                              const float* __restrict__ siga,
                                              const float* __restrict__ conv_w,
                                              const float* __restrict__ conv_b,
                                              float* __restrict__ out,
                                              float* __restrict__ bnsum,
                                              float* __restrict__ bnsq) {
  __shared__ __attribute__((aligned(16))) float in_lds[4 * 5 * 132]; // 10.6 KB
  __shared__ float w_lds[288 * 32];                                  // 36 KB
  const int tid = threadIdx.x;
  const int oc = tid & 31;
  const int g = tid >> 5;
  const int b = blockIdx.x >> 5;
  const int oh0 = (blockIdx.x & 31) * 2;
  const int ih0 = 2 * oh0 - 1; // rows ih0..ih0+4

  for (int i = tid; i < 288 * 32; i += 256) {
    int oc_ = i / 288, rem = i % 288;
    w_lds[rem * 32 + oc_] = conv_w[i];
  }

  float acc[2][8];
#pragma unroll
  for (int a = 0; a < 2; ++a)
#pragma unroll
    for (int o = 0; o < 8; ++o) acc[a][o] = 0.f;

  const float* sgb = siga + (size_t)b * HW_;

  for (int chunk = 0; chunk < 8; ++chunk) {
    __syncthreads();
    for (int i = tid; i < 4 * 5 * 132; i += 256) {
      int icl = i / 660;
      int rem = i % 660;
      int r = rem / 132, col = rem % 132;
      int ih = ih0 + r, iw = col - 1;
      float v = 0.f;
      if (ih >= 0 && ih < H_ && iw >= 0 && iw < W_) {
        int pp = ih * W_ + iw;
        v = xc[((size_t)b * OC_ + (chunk * 4 + icl)) * HW_ + pp] * sgb[pp];
      }
      in_lds[i] = v;
    }
    __syncthreads();
#pragma unroll
    for (int icl = 0; icl < 4; ++icl) {
      const int wb = (chunk * 4 + icl) * 9 * 32 + oc;
#pragma unroll
      for (int r = 0; r < 5; ++r) {
        float f[20] __attribute__((aligned(16)));
        const float4* s4 = (const float4*)&in_lds[(icl * 5 + r) * 132 + 16 * g];
#pragma unroll
        for (int j = 0; j < 5; ++j) ((float4*)f)[j] = s4[j];
#pragma unroll
        for (int ohl = 0; ohl < 2; ++ohl) {
          const int kh = r - 2 * ohl;
          if (kh < 0 || kh > 2) continue; // compile-time after unroll
          float w0 = w_lds[wb + (kh * 3 + 0) * 32];
          float w1 = w_lds[wb + (kh * 3 + 1) * 32];
          float w2 = w_lds[wb + (kh * 3 + 2) * 32];
#pragma unroll
          for (int o = 0; o < 8; ++o)
            acc[ohl][o] += f[2 * o] * w0 + f[2 * o + 1] * w1 + f[2 * o + 2] * w2;
        }
      }
    }
  }

  float bias = conv_b[oc];
  float lsum = 0.f, lsq = 0.f;
  float* outp = out + ((size_t)b * OC_ + oc) * (OH_ * OW_) + (size_t)oh0 * OW_ + g * 8;
#pragma unroll
  for (int ohl = 0; ohl < 2; ++ohl) {
    float vout[8] __attribute__((aligned(16)));
#pragma unroll
    for (int o = 0; o < 8; ++o) {
      float v = acc[ohl][o] + bias;
      vout[o] = v;
      lsum += v;
      lsq += v * v;
    }
    *((float4*)(outp + ohl * OW_)) = *(float4*)&vout[0];
    *((float4*)(outp + ohl * OW_ + 4)) = *(float4*)&vout[4];
  }
  __syncthreads(); // done reading in_lds; reuse for reduction
  in_lds[tid] = lsum;
  in_lds[256 + tid] = lsq;
  __syncthreads();
  if (tid < 32) {
    float t = 0.f, tq = 0.f;
#pragma unroll
    for (int gg = 0; gg < 8; ++gg) {
      t += in_lds[gg * 32 + tid];
      tq += in_lds[256 + gg * 32 + tid];
    }
    atomicAdd(&bnsum[tid], t);
    atomicAdd(&bnsq[tid], tq);
  }
}

// ---------------- 8. BN finalize (redundant per block) + apply + SiLU ------
__global__ __launch_bounds__(256) void k_apply(float* __restrict__ out,
                                               const float* __restrict__ sum,
                                               const float* __restrict__ sq,
                                               const float* __restrict__ gamma,
                                               const float* __restrict__ beta) {
  __shared__ float ssc[OC_], ssh[OC_];
  if (threadIdx.x < OC_) {
    int i = threadIdx.x;
    const float N = (float)(B_ * OH_ * OW_);
    float mu = sum[i] / N;
    float var = sq[i] / N - mu * mu; // population var (ddof=0)
    float sc = gamma[i] / sqrtf(var + BN_EPS);
    ssc[i] = sc;
    ssh[i] = beta[i] - mu * sc;
  }
  __syncthreads();
  int idx4 = blockIdx.x * 256 + threadIdx.x; // over out_size/4 = 524288
  int oc = (idx4 >> 10) & 31;                // 1024 float4 per (b,oc) plane
  float sc = ssc[oc], sh = ssh[oc];
  float4 v = ((float4*)out)[idx4];
  float t;
  t = v.x * sc + sh; v.x = t / (1.0f + __expf(-t));
  t = v.y * sc + sh; v.y = t / (1.0f + __expf(-t));
  t = v.z * sc + sh; v.z = t / (1.0f + __expf(-t));
  t = v.w * sc + sh; v.w = t / (1.0f + __expf(-t));
  ((float4*)out)[idx4] = v;
}

extern "C" void kernel_launch(void* const* d_in, const int* in_sizes, int n_in,
                              void* d_out, int out_size, void* d_ws, size_t ws_size,
                              hipStream_t stream) {
  const float* x      = (const float*)d_in[0];
  const float* lw     = (const float*)d_in[1];
  const float* lb     = (const float*)d_in[2];
  const float* lsa_w  = (const float*)d_in[3];
  const float* conv_w = (const float*)d_in[4];
  const float* conv_b = (const float*)d_in[5];
  const float* gamma  = (const float*)d_in[6];
  const float* beta   = (const float*)d_in[7];
  float* out = (float*)d_out;
  float* ws = (float*)d_ws;

  hipMemsetAsync(ws + OFF_BNSUM, 0, 64 * sizeof(float), stream); // sums+sumsq

  k_pool<<<B_ * C_, 256, 0, stream>>>(x, ws + OFF_XP);
  k_feat<<<B_, 256, 0, stream>>>(ws + OFF_XP, ws + OFF_FEAT);
  k_attn<<<1, 256, 0, stream>>>(ws + OFF_FEAT, lw, lb,
                                (int*)(ws + OFF_MAXID), ws + OFF_SCALE);
  k_build<<<1024, 256, 0, stream>>>(x, (const int*)(ws + OFF_MAXID), ws + OFF_SCALE,
                                    ws + OFF_XC, ws + OFF_SMEAN, ws + OFF_SMAX);
  k_lsa<<<1024, 256, 0, stream>>>(ws + OFF_SMEAN, ws + OFF_SMAX, lsa_w, ws + OFF_SIGA);
  k_conv<<<512, 256, 0, stream>>>(ws + OFF_XC, ws + OFF_SIGA, conv_w, conv_b, out,
                                  ws + OFF_BNSUM, ws + OFF_BNSQ);
  k_apply<<<2048, 256, 0, stream>>>(out, ws + OFF_BNSUM, ws + OFF_BNSQ, gamma, beta);
}

// Round 3
// 522.627 us; speedup vs baseline: 1.3964x; 1.2961x over previous
//
#include <hip/hip_runtime.h>
#include <math.h>

#define B_ 16
#define C_ 256
#define H_ 128
#define W_ 128
#define HW_ (H_*W_)
#define PO 20
#define NPOOL (PO*PO)
#define MID_ 16
#define OC_ 32
#define OH_ 64
#define OW_ 64
#define BN_EPS 1e-3f

// workspace offsets in floats
#define OFF_XP     0
#define OFF_FEAT   1638400
#define OFF_SCORE  1642496
#define OFF_MAXID  1642752
#define OFF_SCALE  1642768
#define OFF_BNSUM  1642784
#define OFF_BNSQ   1642816
#define OFF_SMEAN  1642848
#define OFF_SMAX   1904992
#define OFF_SIGA   2167136
#define OFF_XC     2429280

// adaptive-pool bin start/end for n=128 -> 20 (H and W identical)
__device__ __forceinline__ int bin_s(int p) { return (p * 128) / 20; }
__device__ __forceinline__ int bin_e(int p) { return ((p + 1) * 128 + 19) / 20; }

// ---------------- 1. fused pool + group-mean --------------------------------
// Key fact: any aligned 32-element chunk of the 128->20 pooling has the same
// relative bin pattern S={0,6,12,19,25}, E={7,13,20,26,32} (bins overlap; an
// element may feed two bins). Block = (b, group g of 16 ch, row-half rh).
// Thread = (row hl 0..63, col-quarter q 0..3) owns 32 cols; loops all 16
// channels: col-bins (compile-time membership) + accumulates the group sum in
// 8 float4 registers -> writes group-mean channel straight into xc[16+g].
__global__ __launch_bounds__(256) void k_pool2(const float* __restrict__ x,
                                               float* __restrict__ xp,
                                               float* __restrict__ xc) {
  __shared__ float tmp[64 * 21]; // 5.25 KB, +1 pad
  const int blk = blockIdx.x;
  const int b = blk >> 5, g = (blk >> 1) & 15, rh = blk & 1;
  const int tid = threadIdx.x;
  const int hl = tid >> 2, q = tid & 3;
  const int hg = rh * 64 + hl;
  const float* rowbase = x + (size_t)(b * C_) * HW_ + (size_t)hg * W_ + q * 32;

  float4 xacc[8];
#pragma unroll
  for (int j = 0; j < 8; ++j) xacc[j] = make_float4(0.f, 0.f, 0.f, 0.f);

  for (int k = 0; k < 16; ++k) {
    const int c = g * 16 + k;
    const float4* src4 = (const float4*)(rowbase + (size_t)c * HW_);
    float bin[5];
#pragma unroll
    for (int p = 0; p < 5; ++p) bin[p] = 0.f;
#pragma unroll
    for (int j = 0; j < 8; ++j) {
      float4 v = src4[j];
      xacc[j].x += v.x; xacc[j].y += v.y; xacc[j].z += v.z; xacc[j].w += v.w;
      const float c4[4] = {v.x, v.y, v.z, v.w};
#pragma unroll
      for (int kk = 0; kk < 4; ++kk) {
        const int cc = 4 * j + kk;
#pragma unroll
        for (int p = 0; p < 5; ++p) {
          const int S = (p * 32) / 5;            // 0,6,12,19,25
          const int E = ((p + 1) * 32 + 4) / 5;  // 7,13,20,26,32
          if (cc >= S && cc < E) bin[p] += c4[kk]; // folds at compile time
        }
      }
    }
#pragma unroll
    for (int p = 0; p < 5; ++p) {
      const int S = (p * 32) / 5, E = ((p + 1) * 32 + 4) / 5;
      tmp[hl * 21 + q * 5 + p] = bin[p] / (float)(E - S);
    }
    __syncthreads();
    if (tid < 200) { // row-pool: 10 output rows x 20 cols for this channel
      const int ol = tid / 20, p = tid % 20;
      const int o = rh * 10 + ol;
      const int rs = bin_s(o), re = bin_e(o);
      float s = 0.f;
      for (int r = rs; r < re; ++r) s += tmp[(r - rh * 64) * 21 + p];
      xp[(size_t)(b * C_ + c) * NPOOL + o * PO + p] = s / (float)(re - rs);
    }
    __syncthreads();
  }
  // write group-mean channel directly into xc[b][16+g]
  float4* dst = (float4*)(xc + (size_t)(b * OC_ + MID_ + g) * HW_ + (size_t)hg * W_ + q * 32);
#pragma unroll
  for (int j = 0; j < 8; ++j) {
    float4 v = xacc[j];
    v.x *= 0.0625f; v.y *= 0.0625f; v.z *= 0.0625f; v.w *= 0.0625f;
    dst[j] = v;
  }
}

// ---------------- 2. feat[b,i] = (1/(399*256)) * (sum_n xp[i,n]*s[n] - m_i*S)
__global__ __launch_bounds__(256) void k_feat(const float* __restrict__ xp,
                                              float* __restrict__ feat) {
  const int b = blockIdx.x;
  const float* base = xp + (size_t)b * C_ * NPOOL;
  const int tid = threadIdx.x;
  __shared__ float sn[NPOOL];
  __shared__ float red[256];
  const float4* row4 = (const float4*)(base + tid * NPOOL);
  float rs = 0.f;
#pragma unroll 4
  for (int n = 0; n < NPOOL / 4; ++n) {
    float4 v = row4[n];
    rs += v.x + v.y + v.z + v.w;
  }
  float m = rs / (float)NPOOL;
  red[tid] = m;
  __syncthreads();
  for (int s = 128; s > 0; s >>= 1) {
    if (tid < s) red[tid] += red[tid + s];
    __syncthreads();
  }
  float totm = red[0];
  for (int n = tid; n < NPOOL; n += 256) {
    float cs = 0.f;
    for (int c = 0; c < C_; ++c) cs += base[c * NPOOL + n];
    sn[n] = cs - totm;
  }
  __syncthreads();
  float Sl = 0.f;
  for (int n = tid; n < NPOOL; n += 256) Sl += sn[n];
  red[tid] = Sl;
  __syncthreads();
  for (int s = 128; s > 0; s >>= 1) {
    if (tid < s) red[tid] += red[tid + s];
    __syncthreads();
  }
  float S = red[0];
  float acc = 0.f;
#pragma unroll 4
  for (int n4 = 0; n4 < NPOOL / 4; ++n4) {
    float4 v = row4[n4];
    acc += v.x * sn[4 * n4] + v.y * sn[4 * n4 + 1] + v.z * sn[4 * n4 + 2] + v.w * sn[4 * n4 + 3];
  }
  feat[b * C_ + tid] = (acc - m * S) / ((float)(NPOOL - 1) * (float)C_);
}

// ---------------- 3. score[j] = mean_b sigmoid(feat@W^T+b), 16 blocks ------
__global__ __launch_bounds__(256) void k_attn(const float* __restrict__ feat,
                                              const float* __restrict__ lw,
                                              const float* __restrict__ lb,
                                              float* __restrict__ score) {
  __shared__ float sf[B_ * 257];   // +1 pad per row: kills 16-way conflicts
  __shared__ float wc[16 * 257];
  __shared__ float zs[16 * 17];
  const int tid = threadIdx.x;
  const int j0 = blockIdx.x * 16;
  for (int i = tid; i < B_ * C_; i += 256) sf[(i >> 8) * 257 + (i & 255)] = feat[i];
  for (int i = tid; i < 16 * C_; i += 256)
    wc[(i >> 8) * 257 + (i & 255)] = lw[(size_t)(j0 + (i >> 8)) * C_ + (i & 255)];
  __syncthreads();
  const int jl = tid >> 4, bb = tid & 15;
  float z = 0.f;
#pragma unroll 8
  for (int i = 0; i < C_; ++i) z += sf[bb * 257 + i] * wc[jl * 257 + i];
  z += lb[j0 + jl];
  zs[jl * 17 + bb] = 1.0f / (1.0f + expf(-z)); // accurate expf: gaps ~1e-6
  __syncthreads();
  if (tid < 16) {
    float s = 0.f;
#pragma unroll
    for (int k = 0; k < 16; ++k) s += zs[tid * 17 + k];
    score[j0 + tid] = s / (float)B_;
  }
}

// ---------------- 4. stable top-16 (descending, ties by index), sorted asc
__global__ __launch_bounds__(256) void k_select(const float* __restrict__ score,
                                                int* __restrict__ max_id,
                                                float* __restrict__ scale) {
  __shared__ float ss[C_];
  __shared__ int flag[C_];
  const int tid = threadIdx.x;
  ss[tid] = score[tid];
  __syncthreads();
  float my = ss[tid];
  int rank = 0;
  for (int k = 0; k < C_; ++k) {
    float v = ss[k];
    rank += (v > my || (v == my && k < tid)) ? 1 : 0;
  }
  flag[tid] = (rank < MID_) ? 1 : 0;
  __syncthreads();
  if (rank < MID_) {
    int pos = 0;
    for (int k = 0; k < tid; ++k) pos += flag[k];
    max_id[pos] = tid;
    scale[pos] = 1.0f + my;
  }
}

// ---------------- 5. build xc[0..15] = gathered*scale, + channel mean/max --
// xc[16..31] already written by k_pool2; read back for mean/max only.
__global__ __launch_bounds__(128) void k_build(const float* __restrict__ x,
                                               const int* __restrict__ max_id,
                                               const float* __restrict__ scale,
                                               float* __restrict__ xc,
                                               float* __restrict__ smean,
                                               float* __restrict__ smax) {
  __shared__ int mid_s[MID_];
  __shared__ float sc_s[MID_];
  if (threadIdx.x < MID_) {
    mid_s[threadIdx.x] = max_id[threadIdx.x];
    sc_s[threadIdx.x] = scale[threadIdx.x];
  }
  __syncthreads();
  const int P = blockIdx.x * 128 + threadIdx.x; // over B*HW/4 = 65536
  const int b = P >> 12, pix4 = P & 4095;
  const float4* xb = (const float4*)x + (size_t)(b * C_) * (HW_ / 4) + pix4;
  float4* xcb = (float4*)xc + (size_t)(b * OC_) * (HW_ / 4) + pix4;
  float4 ms = make_float4(0.f, 0.f, 0.f, 0.f);
  float4 mx = make_float4(-INFINITY, -INFINITY, -INFINITY, -INFINITY);
#pragma unroll
  for (int m = 0; m < MID_; ++m) {
    float4 t = xb[(size_t)mid_s[m] * (HW_ / 4)];
    float sc = sc_s[m];
    t.x *= sc; t.y *= sc; t.z *= sc; t.w *= sc;
    xcb[(size_t)m * (HW_ / 4)] = t;
    ms.x += t.x; ms.y += t.y; ms.z += t.z; ms.w += t.w;
    mx.x = fmaxf(mx.x, t.x); mx.y = fmaxf(mx.y, t.y);
    mx.z = fmaxf(mx.z, t.z); mx.w = fmaxf(mx.w, t.w);
  }
#pragma unroll
  for (int g = 0; g < MID_; ++g) {
    float4 t = xcb[(size_t)(MID_ + g) * (HW_ / 4)];
    ms.x += t.x; ms.y += t.y; ms.z += t.z; ms.w += t.w;
    mx.x = fmaxf(mx.x, t.x); mx.y = fmaxf(mx.y, t.y);
    mx.z = fmaxf(mx.z, t.z); mx.w = fmaxf(mx.w, t.w);
  }
  ms.x *= (1.f / 32.f); ms.y *= (1.f / 32.f); ms.z *= (1.f / 32.f); ms.w *= (1.f / 32.f);
  ((float4*)smean)[P] = ms;
  ((float4*)smax)[P] = mx;
}

// ---------------- 6. LSA 7x7 conv (2->1) pad 3 + sigmoid ------------------
__global__ __launch_bounds__(256) void k_lsa(const float* __restrict__ smean,
                                             const float* __restrict__ smax,
                                             const float* __restrict__ lsa_w,
                                             float* __restrict__ siga) {
  __shared__ float w0[49], w1[49];
  if (threadIdx.x < 49) {
    w0[threadIdx.x] = lsa_w[threadIdx.x];
    w1[threadIdx.x] = lsa_w[49 + threadIdx.x];
  }
  __syncthreads();
  int idx = blockIdx.x * 256 + threadIdx.x; // over B*HW
  int b = idx >> 14;
  int pix = idx & (HW_ - 1);
  int h = pix >> 7, w = pix & 127;
  const float* pm = smean + (size_t)b * HW_;
  const float* px = smax + (size_t)b * HW_;
  float acc = 0.f;
  for (int kh = 0; kh < 7; ++kh) {
    int ih = h + kh - 3;
    if (ih < 0 || ih >= H_) continue;
    for (int kw = 0; kw < 7; ++kw) {
      int iw = w + kw - 3;
      if (iw < 0 || iw >= W_) continue;
      int p = ih * W_ + iw;
      acc += pm[p] * w0[kh * 7 + kw] + px[p] * w1[kh * 7 + kw];
    }
  }
  siga[idx] = 1.0f / (1.0f + __expf(-acc));
}

// ---------------- 7. conv 3x3 stride2 pad1 (32->32) + bias + BN partials ---
__global__ __launch_bounds__(256) void k_conv(const float* __restrict__ xc,
                                              const float* __restrict__ siga,
                                              const float* __restrict__ conv_w,
                                              const float* __restrict__ conv_b,
                                              float* __restrict__ out,
                                              float* __restrict__ bnsum,
                                              float* __restrict__ bnsq) {
  __shared__ __attribute__((aligned(16))) float in_lds[4 * 5 * 132]; // 10.6 KB
  __shared__ float w_lds[288 * 32];                                  // 36 KB
  const int tid = threadIdx.x;
  const int oc = tid & 31;
  const int g = tid >> 5;
  const int b = blockIdx.x >> 5;
  const int oh0 = (blockIdx.x & 31) * 2;
  const int ih0 = 2 * oh0 - 1; // rows ih0..ih0+4

  for (int i = tid; i < 288 * 32; i += 256) {
    int oc_ = i / 288, rem = i % 288;
    w_lds[rem * 32 + oc_] = conv_w[i];
  }

  float acc[2][8];
#pragma unroll
  for (int a = 0; a < 2; ++a)
#pragma unroll
    for (int o = 0; o < 8; ++o) acc[a][o] = 0.f;

  const float* sgb = siga + (size_t)b * HW_;

  for (int chunk = 0; chunk < 8; ++chunk) {
    __syncthreads();
    for (int i = tid; i < 4 * 5 * 132; i += 256) {
      int icl = i / 660;
      int rem = i % 660;
      int r = rem / 132, col = rem % 132;
      int ih = ih0 + r, iw = col - 1;
      float v = 0.f;
      if (ih >= 0 && ih < H_ && iw >= 0 && iw < W_) {
        int pp = ih * W_ + iw;
        v = xc[((size_t)(b * OC_) + (chunk * 4 + icl)) * HW_ + pp] * sgb[pp];
      }
      in_lds[i] = v;
    }
    __syncthreads();
#pragma unroll
    for (int icl = 0; icl < 4; ++icl) {
      const int wb = (chunk * 4 + icl) * 9 * 32 + oc;
#pragma unroll
      for (int r = 0; r < 5; ++r) {
        float f[20] __attribute__((aligned(16)));
        const float4* s4 = (const float4*)&in_lds[(icl * 5 + r) * 132 + 16 * g];
#pragma unroll
        for (int j = 0; j < 5; ++j) ((float4*)f)[j] = s4[j];
#pragma unroll
        for (int ohl = 0; ohl < 2; ++ohl) {
          const int kh = r - 2 * ohl;
          if (kh < 0 || kh > 2) continue; // compile-time after unroll
          float w0 = w_lds[wb + (kh * 3 + 0) * 32];
          float w1 = w_lds[wb + (kh * 3 + 1) * 32];
          float w2 = w_lds[wb + (kh * 3 + 2) * 32];
#pragma unroll
          for (int o = 0; o < 8; ++o)
            acc[ohl][o] += f[2 * o] * w0 + f[2 * o + 1] * w1 + f[2 * o + 2] * w2;
        }
      }
    }
  }

  float bias = conv_b[oc];
  float lsum = 0.f, lsq = 0.f;
  float* outp = out + ((size_t)(b * OC_) + oc) * (OH_ * OW_) + (size_t)oh0 * OW_ + g * 8;
#pragma unroll
  for (int ohl = 0; ohl < 2; ++ohl) {
    float vout[8] __attribute__((aligned(16)));
#pragma unroll
    for (int o = 0; o < 8; ++o) {
      float v = acc[ohl][o] + bias;
      vout[o] = v;
      lsum += v;
      lsq += v * v;
    }
    *((float4*)(outp + ohl * OW_)) = *(float4*)&vout[0];
    *((float4*)(outp + ohl * OW_ + 4)) = *(float4*)&vout[4];
  }
  __syncthreads(); // done reading in_lds; reuse for reduction
  in_lds[tid] = lsum;
  in_lds[256 + tid] = lsq;
  __syncthreads();
  if (tid < 32) {
    float t = 0.f, tq = 0.f;
#pragma unroll
    for (int gg = 0; gg < 8; ++gg) {
      t += in_lds[gg * 32 + tid];
      tq += in_lds[256 + gg * 32 + tid];
    }
    atomicAdd(&bnsum[tid], t);
    atomicAdd(&bnsq[tid], tq);
  }
}

// ---------------- 8. BN finalize (redundant per block) + apply + SiLU ------
__global__ __launch_bounds__(256) void k_apply(float* __restrict__ out,
                                               const float* __restrict__ sum,
                                               const float* __restrict__ sq,
                                               const float* __restrict__ gamma,
                                               const float* __restrict__ beta) {
  __shared__ float ssc[OC_], ssh[OC_];
  if (threadIdx.x < OC_) {
    int i = threadIdx.x;
    const float N = (float)(B_ * OH_ * OW_);
    float mu = sum[i] / N;
    float var = sq[i] / N - mu * mu; // population var (ddof=0)
    float sc = gamma[i] / sqrtf(var + BN_EPS);
    ssc[i] = sc;
    ssh[i] = beta[i] - mu * sc;
  }
  __syncthreads();
  int idx4 = blockIdx.x * 256 + threadIdx.x; // over out_size/4 = 524288
  int oc = (idx4 >> 10) & 31;                // 1024 float4 per (b,oc) plane
  float sc = ssc[oc], sh = ssh[oc];
  float4 v = ((float4*)out)[idx4];
  float t;
  t = v.x * sc + sh; v.x = t / (1.0f + __expf(-t));
  t = v.y * sc + sh; v.y = t / (1.0f + __expf(-t));
  t = v.z * sc + sh; v.z = t / (1.0f + __expf(-t));
  t = v.w * sc + sh; v.w = t / (1.0f + __expf(-t));
  ((float4*)out)[idx4] = v;
}

extern "C" void kernel_launch(void* const* d_in, const int* in_sizes, int n_in,
                              void* d_out, int out_size, void* d_ws, size_t ws_size,
                              hipStream_t stream) {
  const float* x      = (const float*)d_in[0];
  const float* lw     = (const float*)d_in[1];
  const float* lb     = (const float*)d_in[2];
  const float* lsa_w  = (const float*)d_in[3];
  const float* conv_w = (const float*)d_in[4];
  const float* conv_b = (const float*)d_in[5];
  const float* gamma  = (const float*)d_in[6];
  const float* beta   = (const float*)d_in[7];
  float* out = (float*)d_out;
  float* ws = (float*)d_ws;

  hipMemsetAsync(ws + OFF_BNSUM, 0, 64 * sizeof(float), stream); // sums+sumsq

  k_pool2<<<512, 256, 0, stream>>>(x, ws + OFF_XP, ws + OFF_XC);
  k_feat<<<B_, 256, 0, stream>>>(ws + OFF_XP, ws + OFF_FEAT);
  k_attn<<<16, 256, 0, stream>>>(ws + OFF_FEAT, lw, lb, ws + OFF_SCORE);
  k_select<<<1, 256, 0, stream>>>(ws + OFF_SCORE, (int*)(ws + OFF_MAXID), ws + OFF_SCALE);
  k_build<<<512, 128, 0, stream>>>(x, (const int*)(ws + OFF_MAXID), ws + OFF_SCALE,
                                   ws + OFF_XC, ws + OFF_SMEAN, ws + OFF_SMAX);
  k_lsa<<<1024, 256, 0, stream>>>(ws + OFF_SMEAN, ws + OFF_SMAX, lsa_w, ws + OFF_SIGA);
  k_conv<<<512, 256, 0, stream>>>(ws + OFF_XC, ws + OFF_SIGA, conv_w, conv_b, out,
                                  ws + OFF_BNSUM, ws + OFF_BNSQ);
  k_apply<<<2048, 256, 0, stream>>>(out, ws + OFF_BNSUM, ws + OFF_BNSQ, gamma, beta);
}

// Round 4
// 517.594 us; speedup vs baseline: 1.4100x; 1.0097x over previous
//
#include <hip/hip_runtime.h>
#include <math.h>

#define B_ 16
#define C_ 256
#define H_ 128
#define W_ 128
#define HW_ (H_*W_)
#define PO 20
#define NPOOL (PO*PO)
#define MID_ 16
#define OC_ 32
#define OH_ 64
#define OW_ 64
#define BN_EPS 1e-3f

// workspace offsets in floats (~11.9 MB total)
#define OFF_XP     0
#define OFF_SN     1638400
#define OFF_FEAT   1644800
#define OFF_SCORE  1648896
#define OFF_MAXID  1649152
#define OFF_SCALE  1649168
#define OFF_BNSUM  1649184
#define OFF_BNSQ   1649216
#define OFF_SMEAN  1649248
#define OFF_SMAX   1911392
#define OFF_SIGA   2173536
#define OFF_XC     2435680

// adaptive-pool bin start/end for n=128 -> 20 (H and W identical)
__device__ __forceinline__ int bin_s(int p) { return (p * 128) / 20; }
__device__ __forceinline__ int bin_e(int p) { return ((p + 1) * 128 + 19) / 20; }

// ---------------- 1. fused pool + group-mean + column-sum -------------------
// Aligned 32-col chunks share the relative bin pattern S={0,6,12,19,25},
// E={7,13,20,26,32} (bins overlap; an element may feed two bins).
// Block=(b, group g, row-half rh). Thread=(row hl, col-quarter q).
// Produces: xp (pooled), xc[16+g] (group mean), sn[b][n]=sum_c xp (atomics).
// tmp is double-buffered: ONE barrier per channel (each __syncthreads drains
// vmcnt(0) on gfx950 -- halving barriers halves exposed HBM latency).
__global__ __launch_bounds__(256) void k_pool2(const float* __restrict__ x,
                                               float* __restrict__ xp,
                                               float* __restrict__ sn,
                                               float* __restrict__ xc) {
  __shared__ float tmp[2][64 * 21]; // 10.5 KB
  const int blk = blockIdx.x;
  const int b = blk >> 5, g = (blk >> 1) & 15, rh = blk & 1;
  const int tid = threadIdx.x;
  const int hl = tid >> 2, q = tid & 3;
  const int hg = rh * 64 + hl;
  const float* rowbase = x + (size_t)(b * C_) * HW_ + (size_t)hg * W_ + q * 32;

  float4 xacc[8];
#pragma unroll
  for (int j = 0; j < 8; ++j) xacc[j] = make_float4(0.f, 0.f, 0.f, 0.f);
  float snacc = 0.f;

  for (int k = 0; k < 16; ++k) {
    const int c = g * 16 + k;
    const float4* src4 = (const float4*)(rowbase + (size_t)c * HW_);
    float bin[5];
#pragma unroll
    for (int p = 0; p < 5; ++p) bin[p] = 0.f;
#pragma unroll
    for (int j = 0; j < 8; ++j) {
      float4 v = src4[j];
      xacc[j].x += v.x; xacc[j].y += v.y; xacc[j].z += v.z; xacc[j].w += v.w;
      const float c4[4] = {v.x, v.y, v.z, v.w};
#pragma unroll
      for (int kk = 0; kk < 4; ++kk) {
        const int cc = 4 * j + kk;
#pragma unroll
        for (int p = 0; p < 5; ++p) {
          const int S = (p * 32) / 5;            // 0,6,12,19,25
          const int E = ((p + 1) * 32 + 4) / 5;  // 7,13,20,26,32
          if (cc >= S && cc < E) bin[p] += c4[kk]; // folds at compile time
        }
      }
    }
    float* tb = tmp[k & 1];
#pragma unroll
    for (int p = 0; p < 5; ++p) {
      const int S = (p * 32) / 5, E = ((p + 1) * 32 + 4) / 5;
      tb[hl * 21 + q * 5 + p] = bin[p] / (float)(E - S);
    }
    __syncthreads();
    if (tid < 200) { // 10 output rows x 20 cols for this channel
      const int ol = tid / 20, p = tid % 20;
      const int o = rh * 10 + ol;
      const int rs = bin_s(o), re = bin_e(o);
      float s = 0.f;
      for (int r = rs; r < re; ++r) s += tb[(r - rh * 64) * 21 + p];
      float v = s / (float)(re - rs);
      xp[(size_t)(b * C_ + c) * NPOOL + o * PO + p] = v;
      snacc += v;
    }
    // no second barrier: next iter writes tmp[(k+1)&1]; reuse of this buffer
    // (iter k+2) happens only after barrier k+1, when all readers are done.
  }
  if (tid < 200) atomicAdd(&sn[b * NPOOL + rh * 200 + tid], snacc);
  // group-mean channel -> xc[b][16+g]
  float4* dst = (float4*)(xc + (size_t)(b * OC_ + MID_ + g) * HW_ + (size_t)hg * W_ + q * 32);
#pragma unroll
  for (int j = 0; j < 8; ++j) {
    float4 v = xacc[j];
    v.x *= 0.0625f; v.y *= 0.0625f; v.z *= 0.0625f; v.w *= 0.0625f;
    dst[j] = v;
  }
}

// ---------------- 2. feat from xp + precomputed column sums ----------------
// feat[b,i] = (dot_i - totm*rs_i - m_i*S) / (399*256), where
// snraw[n]=sum_c xp[b,c,n] (from k_pool2), totm = sum_c mean_c,
// S = sum_n snraw - 400*totm, dot_i = sum_n xp[i,n]*snraw[n].
__global__ __launch_bounds__(256) void k_feat(const float* __restrict__ xp,
                                              const float* __restrict__ sn,
                                              float* __restrict__ feat) {
  const int b = blockIdx.x;
  const int tid = threadIdx.x;
  __shared__ float snl[NPOOL];
  __shared__ float red[256];
  const float4* row4 = (const float4*)(xp + (size_t)(b * C_ + tid) * NPOOL);
  for (int i = tid; i < NPOOL; i += 256) snl[i] = sn[b * NPOOL + i];
  float rs = 0.f;
#pragma unroll 4
  for (int n = 0; n < NPOOL / 4; ++n) {
    float4 v = row4[n];
    rs += v.x + v.y + v.z + v.w;
  }
  red[tid] = rs;
  __syncthreads();
  for (int s = 128; s > 0; s >>= 1) {
    if (tid < s) red[tid] += red[tid + s];
    __syncthreads();
  }
  const float totm = red[0] / (float)NPOOL; // sum_c mean_c
  __syncthreads();
  float sl = 0.f;
  for (int i = tid; i < NPOOL; i += 256) sl += snl[i];
  red[tid] = sl;
  __syncthreads();
  for (int s = 128; s > 0; s >>= 1) {
    if (tid < s) red[tid] += red[tid + s];
    __syncthreads();
  }
  const float S = red[0] - (float)NPOOL * totm;
  float dot = 0.f;
#pragma unroll 4
  for (int n4 = 0; n4 < NPOOL / 4; ++n4) {
    float4 v = row4[n4];
    dot += v.x * snl[4 * n4] + v.y * snl[4 * n4 + 1]
         + v.z * snl[4 * n4 + 2] + v.w * snl[4 * n4 + 3];
  }
  const float m = rs / (float)NPOOL;
  feat[b * C_ + tid] = (dot - totm * rs - m * S) / ((float)(NPOOL - 1) * (float)C_);
}

// ---------------- 3. score[j] = mean_b sigmoid(feat@W^T+b), 16 blocks ------
__global__ __launch_bounds__(256) void k_attn(const float* __restrict__ feat,
                                              const float* __restrict__ lw,
                                              const float* __restrict__ lb,
                                              float* __restrict__ score) {
  __shared__ float sf[B_ * 257];   // +1 pad per row
  __shared__ float wc[16 * 257];
  __shared__ float zs[16 * 17];
  const int tid = threadIdx.x;
  const int j0 = blockIdx.x * 16;
  for (int i = tid; i < B_ * C_; i += 256) sf[(i >> 8) * 257 + (i & 255)] = feat[i];
  for (int i = tid; i < 16 * C_; i += 256)
    wc[(i >> 8) * 257 + (i & 255)] = lw[(size_t)(j0 + (i >> 8)) * C_ + (i & 255)];
  __syncthreads();
  const int jl = tid >> 4, bb = tid & 15;
  float z = 0.f;
#pragma unroll 8
  for (int i = 0; i < C_; ++i) z += sf[bb * 257 + i] * wc[jl * 257 + i];
  z += lb[j0 + jl];
  zs[jl * 17 + bb] = 1.0f / (1.0f + expf(-z)); // accurate expf: gaps ~1e-6
  __syncthreads();
  if (tid < 16) {
    float s = 0.f;
#pragma unroll
    for (int k = 0; k < 16; ++k) s += zs[tid * 17 + k];
    score[j0 + tid] = s / (float)B_;
  }
}

// ---------------- 4. stable top-16 (desc, ties by index) + zero BN accums --
__global__ __launch_bounds__(256) void k_select(const float* __restrict__ score,
                                                int* __restrict__ max_id,
                                                float* __restrict__ scale,
                                                float* __restrict__ bnzero) {
  __shared__ float ss[C_];
  __shared__ int flag[C_];
  const int tid = threadIdx.x;
  if (tid < 64) bnzero[tid] = 0.f; // bnsum[32] + bnsq[32]
  ss[tid] = score[tid];
  __syncthreads();
  float my = ss[tid];
  int rank = 0;
  for (int k = 0; k < C_; ++k) {
    float v = ss[k];
    rank += (v > my || (v == my && k < tid)) ? 1 : 0;
  }
  flag[tid] = (rank < MID_) ? 1 : 0;
  __syncthreads();
  if (rank < MID_) {
    int pos = 0;
    for (int k = 0; k < tid; ++k) pos += flag[k];
    max_id[pos] = tid;
    scale[pos] = 1.0f + my;
  }
}

// ---------------- 5. build xc[0..15] = gathered*scale, + channel mean/max --
// 2-way channel split (8 waves/CU) with LDS combine; xc[16..31] from k_pool2.
__global__ __launch_bounds__(256) void k_build(const float* __restrict__ x,
                                               const int* __restrict__ max_id,
                                               const float* __restrict__ scale,
                                               float* __restrict__ xc,
                                               float* __restrict__ smean,
                                               float* __restrict__ smax) {
  __shared__ int mid_s[MID_];
  __shared__ float sc_s[MID_];
  __shared__ float4 ps[128], pm[128];
  const int tid = threadIdx.x;
  if (tid < MID_) {
    mid_s[tid] = max_id[tid];
    sc_s[tid] = scale[tid];
  }
  __syncthreads();
  const int p = tid & 127, s = tid >> 7;
  const int P = blockIdx.x * 128 + p; // over B*HW/4 = 65536
  const int b = P >> 12, pix4 = P & 4095;
  const float4* xb = (const float4*)x + (size_t)(b * C_) * (HW_ / 4) + pix4;
  float4* xcb = (float4*)xc + (size_t)(b * OC_) * (HW_ / 4) + pix4;
  float4 ms = make_float4(0.f, 0.f, 0.f, 0.f);
  float4 mx = make_float4(-INFINITY, -INFINITY, -INFINITY, -INFINITY);
#pragma unroll
  for (int mi = 0; mi < 8; ++mi) {
    int m = s * 8 + mi;
    float4 t = xb[(size_t)mid_s[m] * (HW_ / 4)];
    float sc = sc_s[m];
    t.x *= sc; t.y *= sc; t.z *= sc; t.w *= sc;
    xcb[(size_t)m * (HW_ / 4)] = t;
    ms.x += t.x; ms.y += t.y; ms.z += t.z; ms.w += t.w;
    mx.x = fmaxf(mx.x, t.x); mx.y = fmaxf(mx.y, t.y);
    mx.z = fmaxf(mx.z, t.z); mx.w = fmaxf(mx.w, t.w);
  }
#pragma unroll
  for (int gi = 0; gi < 8; ++gi) {
    float4 t = xcb[(size_t)(MID_ + s * 8 + gi) * (HW_ / 4)];
    ms.x += t.x; ms.y += t.y; ms.z += t.z; ms.w += t.w;
    mx.x = fmaxf(mx.x, t.x); mx.y = fmaxf(mx.y, t.y);
    mx.z = fmaxf(mx.z, t.z); mx.w = fmaxf(mx.w, t.w);
  }
  if (s == 1) { ps[p] = ms; pm[p] = mx; }
  __syncthreads();
  if (s == 0) {
    float4 a = ps[p], m2 = pm[p];
    ms.x = (ms.x + a.x) * (1.f / 32.f); ms.y = (ms.y + a.y) * (1.f / 32.f);
    ms.z = (ms.z + a.z) * (1.f / 32.f); ms.w = (ms.w + a.w) * (1.f / 32.f);
    mx.x = fmaxf(mx.x, m2.x); mx.y = fmaxf(mx.y, m2.y);
    mx.z = fmaxf(mx.z, m2.z); mx.w = fmaxf(mx.w, m2.w);
    ((float4*)smean)[P] = ms;
    ((float4*)smax)[P] = mx;
  }
}

// ---------------- 6. LSA 7x7 conv (2->1) pad 3 + sigmoid ------------------
__global__ __launch_bounds__(256) void k_lsa(const float* __restrict__ smean,
                                             const float* __restrict__ smax,
                                             const float* __restrict__ lsa_w,
                                             float* __restrict__ siga) {
  __shared__ float w0[49], w1[49];
  if (threadIdx.x < 49) {
    w0[threadIdx.x] = lsa_w[threadIdx.x];
    w1[threadIdx.x] = lsa_w[49 + threadIdx.x];
  }
  __syncthreads();
  int idx = blockIdx.x * 256 + threadIdx.x; // over B*HW
  int b = idx >> 14;
  int pix = idx & (HW_ - 1);
  int h = pix >> 7, w = pix & 127;
  const float* pm = smean + (size_t)b * HW_;
  const float* px = smax + (size_t)b * HW_;
  float acc = 0.f;
  for (int kh = 0; kh < 7; ++kh) {
    int ih = h + kh - 3;
    if (ih < 0 || ih >= H_) continue;
    for (int kw = 0; kw < 7; ++kw) {
      int iw = w + kw - 3;
      if (iw < 0 || iw >= W_) continue;
      int p = ih * W_ + iw;
      acc += pm[p] * w0[kh * 7 + kw] + px[p] * w1[kh * 7 + kw];
    }
  }
  siga[idx] = 1.0f / (1.0f + __expf(-acc));
}

// ---------------- 7. conv 3x3 stride2 pad1 (32->32) + bias + BN partials ---
// siga tile staged ONCE per block (reused by all 8 input-channel chunks).
__global__ __launch_bounds__(256) void k_conv(const float* __restrict__ xc,
                                              const float* __restrict__ siga,
                                              const float* __restrict__ conv_w,
                                              const float* __restrict__ conv_b,
                                              float* __restrict__ out,
                                              float* __restrict__ bnsum,
                                              float* __restrict__ bnsq) {
  __shared__ __attribute__((aligned(16))) float in_lds[4 * 5 * 132]; // 10.6 KB
  __shared__ float sg_lds[5 * 132];                                  // 2.6 KB
  __shared__ float w_lds[288 * 32];                                  // 36 KB
  const int tid = threadIdx.x;
  const int oc = tid & 31;
  const int g = tid >> 5;
  const int b = blockIdx.x >> 5;
  const int oh0 = (blockIdx.x & 31) * 2;
  const int ih0 = 2 * oh0 - 1; // rows ih0..ih0+4

  for (int i = tid; i < 288 * 32; i += 256) {
    int oc_ = i / 288, rem = i % 288;
    w_lds[rem * 32 + oc_] = conv_w[i];
  }
  const float* sgb = siga + (size_t)b * HW_;
  for (int i = tid; i < 5 * 132; i += 256) {
    int r = i / 132, col = i % 132;
    int ih = ih0 + r, iw = col - 1;
    float v = 0.f;
    if (ih >= 0 && ih < H_ && iw >= 0 && iw < W_) v = sgb[ih * W_ + iw];
    sg_lds[i] = v;
  }

  float acc[2][8];
#pragma unroll
  for (int a = 0; a < 2; ++a)
#pragma unroll
    for (int o = 0; o < 8; ++o) acc[a][o] = 0.f;

  for (int chunk = 0; chunk < 8; ++chunk) {
    __syncthreads();
    for (int i = tid; i < 4 * 5 * 132; i += 256) {
      int icl = i / 660;
      int rem = i % 660;
      int r = rem / 132, col = rem % 132;
      int ih = ih0 + r, iw = col - 1;
      float v = 0.f;
      if (ih >= 0 && ih < H_ && iw >= 0 && iw < W_) {
        v = xc[((size_t)(b * OC_) + (chunk * 4 + icl)) * HW_ + ih * W_ + iw] * sg_lds[rem];
      }
      in_lds[i] = v;
    }
    __syncthreads();
#pragma unroll
    for (int icl = 0; icl < 4; ++icl) {
      const int wb = (chunk * 4 + icl) * 9 * 32 + oc;
#pragma unroll
      for (int r = 0; r < 5; ++r) {
        float f[20] __attribute__((aligned(16)));
        const float4* s4 = (const float4*)&in_lds[(icl * 5 + r) * 132 + 16 * g];
#pragma unroll
        for (int j = 0; j < 5; ++j) ((float4*)f)[j] = s4[j];
#pragma unroll
        for (int ohl = 0; ohl < 2; ++ohl) {
          const int kh = r - 2 * ohl;
          if (kh < 0 || kh > 2) continue; // compile-time after unroll
          float w0 = w_lds[wb + (kh * 3 + 0) * 32];
          float w1 = w_lds[wb + (kh * 3 + 1) * 32];
          float w2 = w_lds[wb + (kh * 3 + 2) * 32];
#pragma unroll
          for (int o = 0; o < 8; ++o)
            acc[ohl][o] += f[2 * o] * w0 + f[2 * o + 1] * w1 + f[2 * o + 2] * w2;
        }
      }
    }
  }

  float bias = conv_b[oc];
  float lsum = 0.f, lsq = 0.f;
  float* outp = out + ((size_t)(b * OC_) + oc) * (OH_ * OW_) + (size_t)oh0 * OW_ + g * 8;
#pragma unroll
  for (int ohl = 0; ohl < 2; ++ohl) {
    float vout[8] __attribute__((aligned(16)));
#pragma unroll
    for (int o = 0; o < 8; ++o) {
      float v = acc[ohl][o] + bias;
      vout[o] = v;
      lsum += v;
      lsq += v * v;
    }
    *((float4*)(outp + ohl * OW_)) = *(float4*)&vout[0];
    *((float4*)(outp + ohl * OW_ + 4)) = *(float4*)&vout[4];
  }
  __syncthreads(); // done reading in_lds; reuse for reduction
  in_lds[tid] = lsum;
  in_lds[256 + tid] = lsq;
  __syncthreads();
  if (tid < 32) {
    float t = 0.f, tq = 0.f;
#pragma unroll
    for (int gg = 0; gg < 8; ++gg) {
      t += in_lds[gg * 32 + tid];
      tq += in_lds[256 + gg * 32 + tid];
    }
    atomicAdd(&bnsum[tid], t);
    atomicAdd(&bnsq[tid], tq);
  }
}

// ---------------- 8. BN finalize (redundant per block) + apply + SiLU ------
__global__ __launch_bounds__(256) void k_apply(float* __restrict__ out,
                                               const float* __restrict__ sum,
                                               const float* __restrict__ sq,
                                               const float* __restrict__ gamma,
                                               const float* __restrict__ beta) {
  __shared__ float ssc[OC_], ssh[OC_];
  if (threadIdx.x < OC_) {
    int i = threadIdx.x;
    const float N = (float)(B_ * OH_ * OW_);
    float mu = sum[i] / N;
    float var = sq[i] / N - mu * mu; // population var (ddof=0)
    float sc = gamma[i] / sqrtf(var + BN_EPS);
    ssc[i] = sc;
    ssh[i] = beta[i] - mu * sc;
  }
  __syncthreads();
  int idx4 = blockIdx.x * 256 + threadIdx.x; // over out_size/4 = 524288
  int oc = (idx4 >> 10) & 31;                // 1024 float4 per (b,oc) plane
  float sc = ssc[oc], sh = ssh[oc];
  float4 v = ((float4*)out)[idx4];
  float t;
  t = v.x * sc + sh; v.x = t / (1.0f + __expf(-t));
  t = v.y * sc + sh; v.y = t / (1.0f + __expf(-t));
  t = v.z * sc + sh; v.z = t / (1.0f + __expf(-t));
  t = v.w * sc + sh; v.w = t / (1.0f + __expf(-t));
  ((float4*)out)[idx4] = v;
}

extern "C" void kernel_launch(void* const* d_in, const int* in_sizes, int n_in,
                              void* d_out, int out_size, void* d_ws, size_t ws_size,
                              hipStream_t stream) {
  const float* x      = (const float*)d_in[0];
  const float* lw     = (const float*)d_in[1];
  const float* lb     = (const float*)d_in[2];
  const float* lsa_w  = (const float*)d_in[3];
  const float* conv_w = (const float*)d_in[4];
  const float* conv_b = (const float*)d_in[5];
  const float* gamma  = (const float*)d_in[6];
  const float* beta   = (const float*)d_in[7];
  float* out = (float*)d_out;
  float* ws = (float*)d_ws;

  hipMemsetAsync(ws + OFF_SN, 0, B_ * NPOOL * sizeof(float), stream);

  k_pool2<<<512, 256, 0, stream>>>(x, ws + OFF_XP, ws + OFF_SN, ws + OFF_XC);
  k_feat<<<B_, 256, 0, stream>>>(ws + OFF_XP, ws + OFF_SN, ws + OFF_FEAT);
  k_attn<<<16, 256, 0, stream>>>(ws + OFF_FEAT, lw, lb, ws + OFF_SCORE);
  k_select<<<1, 256, 0, stream>>>(ws + OFF_SCORE, (int*)(ws + OFF_MAXID),
                                  ws + OFF_SCALE, ws + OFF_BNSUM);
  k_build<<<512, 256, 0, stream>>>(x, (const int*)(ws + OFF_MAXID), ws + OFF_SCALE,
                                   ws + OFF_XC, ws + OFF_SMEAN, ws + OFF_SMAX);
  k_lsa<<<1024, 256, 0, stream>>>(ws + OFF_SMEAN, ws + OFF_SMAX, lsa_w, ws + OFF_SIGA);
  k_conv<<<512, 256, 0, stream>>>(ws + OFF_XC, ws + OFF_SIGA, conv_w, conv_b, out,
                                  ws + OFF_BNSUM, ws + OFF_BNSQ);
  k_apply<<<2048, 256, 0, stream>>>(out, ws + OFF_BNSUM, ws + OFF_BNSQ, gamma, beta);
}